// Round 1
// baseline (363.378 us; speedup 1.0000x reference)
//
#include <hip/hip_runtime.h>
#include <stdint.h>

typedef __bf16 bf16_t;
typedef bf16_t bf16x8 __attribute__((ext_vector_type(8)));
typedef float f32x4 __attribute__((ext_vector_type(4)));
typedef unsigned short us8 __attribute__((ext_vector_type(8)));
typedef unsigned short us4 __attribute__((ext_vector_type(4)));

#define B_ 4
#define T_ 4096
#define C_ 1024
#define D_ 128

__device__ __forceinline__ uint16_t f2bf(float f) {
    union { float f; uint32_t u; } v; v.f = f;
    uint32_t u = v.u;
    uint32_t r = (u + 0x7fffu + ((u >> 16) & 1u)) >> 16;
    return (uint16_t)r;
}

// ---------------------------------------------------------------------------
// Kernel 1: W[C,D] fp32 -> WT[w][n][k] bf16 (transposed), w in {q,k,v}
// ---------------------------------------------------------------------------
__global__ __launch_bounds__(256) void prep_w(const float* __restrict__ Wq,
                                              const float* __restrict__ Wk,
                                              const float* __restrict__ Wv,
                                              uint16_t* __restrict__ WT) {
    int idx = blockIdx.x * 256 + threadIdx.x;
    if (idx >= 3 * D_ * C_) return;
    int w   = idx / (D_ * C_);
    int rem = idx - w * (D_ * C_);
    int n   = rem / C_;
    int k   = rem - n * C_;
    const float* W = (w == 0) ? Wq : (w == 1) ? Wk : Wv;
    WT[idx] = f2bf(W[(size_t)k * D_ + n]);
}

// ---------------------------------------------------------------------------
// Kernel 2: fused QKV projection. x[16384,1024] fp32 @ W[1024,128] (x3, bf16)
//  -> qb[16384,128] bf16 (row-major), kb same, vT[B][D][T] bf16 (transposed)
// Block: 64 rows of x, 256 threads (4 waves in 2x2), BK=32.
// ---------------------------------------------------------------------------
#define AST 40   // LDS leading-dim pad: 32+8 elems = 80B = 5x16B, 2-way banks

__global__ __launch_bounds__(256) void qkv_gemm(const float* __restrict__ x,
                                                const uint16_t* __restrict__ WT,
                                                uint16_t* __restrict__ qb,
                                                uint16_t* __restrict__ kb,
                                                uint16_t* __restrict__ vT) {
    __shared__ __align__(16) uint16_t A_lds[64 * AST];
    __shared__ __align__(16) uint16_t W_lds[3][128 * AST];

    int tid  = threadIdx.x;
    int lane = tid & 63;
    int wave = tid >> 6;
    int quad = lane >> 4;
    int lx   = lane & 15;
    int wm   = wave >> 1, wn = wave & 1;
    int m0   = blockIdx.x * 64;

    f32x4 acc[3][2][4];
    for (int w = 0; w < 3; w++)
        for (int mf = 0; mf < 2; mf++)
            for (int nf = 0; nf < 4; nf++)
                acc[w][mf][nf] = (f32x4){0.f, 0.f, 0.f, 0.f};

    int arow = tid >> 2, acb = (tid & 3) * 8;       // A staging: 8 floats/thread
    int wnn  = tid & 127, wkk = (tid >> 7) * 16;    // W staging: 16 bf16/thread/w

    for (int k0 = 0; k0 < C_; k0 += 32) {
        // stage A (fp32 -> bf16)
        {
            const float* xp = x + (size_t)(m0 + arow) * C_ + k0 + acb;
            float4 f0 = *(const float4*)xp;
            float4 f1 = *(const float4*)(xp + 4);
            us8 u;
            u[0] = f2bf(f0.x); u[1] = f2bf(f0.y); u[2] = f2bf(f0.z); u[3] = f2bf(f0.w);
            u[4] = f2bf(f1.x); u[5] = f2bf(f1.y); u[6] = f2bf(f1.z); u[7] = f2bf(f1.w);
            *(us8*)&A_lds[arow * AST + acb] = u;
        }
        // stage 3 W tiles (already bf16, transposed)
        for (int w = 0; w < 3; w++) {
            const uint16_t* wp = WT + (size_t)w * (D_ * C_) + (size_t)wnn * C_ + k0 + wkk;
            *(us8*)&W_lds[w][wnn * AST + wkk]     = *(const us8*)wp;
            *(us8*)&W_lds[w][wnn * AST + wkk + 8] = *(const us8*)(wp + 8);
        }
        __syncthreads();

        bf16x8 af[2];
        af[0] = *(const bf16x8*)&A_lds[(wm * 32 + lx) * AST + quad * 8];
        af[1] = *(const bf16x8*)&A_lds[(wm * 32 + 16 + lx) * AST + quad * 8];
        for (int w = 0; w < 3; w++) {
            for (int nf = 0; nf < 4; nf++) {
                bf16x8 bf = *(const bf16x8*)&W_lds[w][(wn * 64 + nf * 16 + lx) * AST + quad * 8];
                acc[w][0][nf] = __builtin_amdgcn_mfma_f32_16x16x32_bf16(af[0], bf, acc[w][0][nf], 0, 0, 0);
                acc[w][1][nf] = __builtin_amdgcn_mfma_f32_16x16x32_bf16(af[1], bf, acc[w][1][nf], 0, 0, 0);
            }
        }
        __syncthreads();
    }

    // epilogue: C-layout row = quad*4+r, col = lx
    for (int mf = 0; mf < 2; mf++) {
        int mbase = m0 + wm * 32 + mf * 16 + quad * 4;
        for (int nf = 0; nf < 4; nf++) {
            int n = wn * 64 + nf * 16 + lx;
            for (int r = 0; r < 4; r++)
                qb[(size_t)(mbase + r) * D_ + n] = f2bf(acc[0][mf][nf][r]);
            for (int r = 0; r < 4; r++)
                kb[(size_t)(mbase + r) * D_ + n] = f2bf(acc[1][mf][nf][r]);
            // v transposed: vT[batch][n][t], 4 consecutive t -> one 8B store
            int batch = mbase >> 12;
            int t     = mbase & 4095;
            us4 pv;
            pv[0] = f2bf(acc[2][mf][nf][0]);
            pv[1] = f2bf(acc[2][mf][nf][1]);
            pv[2] = f2bf(acc[2][mf][nf][2]);
            pv[3] = f2bf(acc[2][mf][nf][3]);
            *(us4*)&vT[(size_t)batch * D_ * T_ + (size_t)n * T_ + t] = pv;
        }
    }
}

// ---------------------------------------------------------------------------
// Kernel 3: flash attention, causal. Block = 64 Q-rows (4 waves x 16 rows),
// iterate K/V in 64-key tiles. Online softmax in MFMA C-layout.
// ---------------------------------------------------------------------------
#define KST 136  // 128+8 elems; 272B = 17x16B; banks 2-way
#define VST 72   // 64+8 elems;  144B = 9x16B;  banks 2-way

__global__ __launch_bounds__(256) void attn(const uint16_t* __restrict__ qb,
                                            const uint16_t* __restrict__ kb,
                                            const uint16_t* __restrict__ vT,
                                            float* __restrict__ out) {
    __shared__ __align__(16) uint16_t K_lds[64 * KST];
    __shared__ __align__(16) uint16_t V_lds[128 * VST];
    __shared__ __align__(16) uint16_t P_lds[4][16 * VST];

    int tid  = threadIdx.x;
    int lane = tid & 63;
    int wave = tid >> 6;
    int quad = lane >> 4;
    int lx   = lane & 15;

    int b     = blockIdx.x;
    int batch = b & 3;
    int jt    = 63 - (b >> 2);   // longest-first dispatch
    int q0    = jt * 64;

    const float scale = 0.08838834764831845f;  // 1/sqrt(128)
    const float L2E   = 1.4426950408889634f;

    // Q fragments: 16 rows x 128 cols per wave, held in registers
    bf16x8 qf[4];
    {
        const uint16_t* qp = qb + (size_t)(batch * T_ + q0 + wave * 16 + lx) * D_ + quad * 8;
        for (int kc = 0; kc < 4; kc++) qf[kc] = *(const bf16x8*)(qp + kc * 32);
    }

    f32x4 o[8];
    for (int i = 0; i < 8; i++) o[i] = (f32x4){0.f, 0.f, 0.f, 0.f};
    float m_i[4], l_i[4];
    for (int r = 0; r < 4; r++) { m_i[r] = -INFINITY; l_i[r] = 0.f; }

    int krow = tid >> 2, kcb = (tid & 3) * 32;  // K staging: 32 elems/thread
    int vd   = tid >> 1, vsb = (tid & 1) * 32;  // V staging: 32 elems/thread

    int niter = jt + 1;
    for (int it = 0; it < niter; it++) {
        int s0 = it * 64;
        // stage K tile [64 keys][128 d]
        {
            const uint16_t* kp = kb + (size_t)(batch * T_ + s0 + krow) * D_ + kcb;
            for (int i = 0; i < 4; i++)
                *(us8*)&K_lds[krow * KST + kcb + i * 8] = *(const us8*)(kp + i * 8);
        }
        // stage V^T tile [128 d][64 keys]
        {
            const uint16_t* vp = vT + (size_t)batch * D_ * T_ + (size_t)vd * T_ + s0 + vsb;
            for (int i = 0; i < 4; i++)
                *(us8*)&V_lds[vd * VST + vsb + i * 8] = *(const us8*)(vp + i * 8);
        }
        __syncthreads();

        // S = Q K^T : 4 col-tiles x 4 k-chunks
        f32x4 s[4];
        for (int nf = 0; nf < 4; nf++) s[nf] = (f32x4){0.f, 0.f, 0.f, 0.f};
        for (int kc = 0; kc < 4; kc++) {
            for (int nf = 0; nf < 4; nf++) {
                bf16x8 kf = *(const bf16x8*)&K_lds[(nf * 16 + lx) * KST + kc * 32 + quad * 8];
                s[nf] = __builtin_amdgcn_mfma_f32_16x16x32_bf16(qf[kc], kf, s[nf], 0, 0, 0);
            }
        }

        // scale + causal mask
        int rowg = q0 + wave * 16 + quad * 4;   // + r
        float p[4][4];
        bool do_mask = (s0 + 63 > q0 + wave * 16);
        for (int nf = 0; nf < 4; nf++) {
            int colg = s0 + nf * 16 + lx;
            for (int r = 0; r < 4; r++) {
                float sv = s[nf][r] * scale;
                if (do_mask && (colg > rowg + r)) sv = -INFINITY;
                p[nf][r] = sv;
            }
        }

        // row max (across 4 nf, then 16 lanes of quarter-group)
        float rm[4];
        for (int r = 0; r < 4; r++) {
            rm[r] = fmaxf(fmaxf(p[0][r], p[1][r]), fmaxf(p[2][r], p[3][r]));
        }
        for (int off = 1; off < 16; off <<= 1)
            for (int r = 0; r < 4; r++)
                rm[r] = fmaxf(rm[r], __shfl_xor(rm[r], off, 64));

        float alpha[4], rs[4];
        for (int r = 0; r < 4; r++) {
            float mn = fmaxf(m_i[r], rm[r]);
            alpha[r] = exp2f((m_i[r] - mn) * L2E);
            m_i[r]   = mn;
            float sum = 0.f;
            for (int nf = 0; nf < 4; nf++) {
                float e = exp2f((p[nf][r] - mn) * L2E);
                p[nf][r] = e;
                sum += e;
            }
            rs[r] = sum;
        }
        for (int off = 1; off < 16; off <<= 1)
            for (int r = 0; r < 4; r++)
                rs[r] += __shfl_xor(rs[r], off, 64);
        for (int r = 0; r < 4; r++) l_i[r] = l_i[r] * alpha[r] + rs[r];
        for (int i = 0; i < 8; i++)
            for (int r = 0; r < 4; r++) o[i][r] *= alpha[r];

        // P (C-layout) -> LDS -> A-layout fragments
        for (int nf = 0; nf < 4; nf++)
            for (int r = 0; r < 4; r++)
                P_lds[wave][(quad * 4 + r) * VST + nf * 16 + lx] = f2bf(p[nf][r]);

        bf16x8 pf[2];
        pf[0] = *(const bf16x8*)&P_lds[wave][lx * VST + quad * 8];
        pf[1] = *(const bf16x8*)&P_lds[wave][lx * VST + 32 + quad * 8];
        for (int nf = 0; nf < 8; nf++) {
            for (int kc = 0; kc < 2; kc++) {
                bf16x8 vf = *(const bf16x8*)&V_lds[(nf * 16 + lx) * VST + kc * 32 + quad * 8];
                o[nf] = __builtin_amdgcn_mfma_f32_16x16x32_bf16(pf[kc], vf, o[nf], 0, 0, 0);
            }
        }
        __syncthreads();
    }

    // epilogue: out fp32 [B*T][D]
    for (int nf = 0; nf < 8; nf++) {
        for (int r = 0; r < 4; r++) {
            size_t row = (size_t)(batch * T_ + q0 + wave * 16 + quad * 4 + r);
            out[row * D_ + nf * 16 + lx] = o[nf][r] / l_i[r];
        }
    }
}

// ---------------------------------------------------------------------------
extern "C" void kernel_launch(void* const* d_in, const int* in_sizes, int n_in,
                              void* d_out, int out_size, void* d_ws, size_t ws_size,
                              hipStream_t stream) {
    const float* x  = (const float*)d_in[0];
    const float* Wq = (const float*)d_in[1];
    const float* Wk = (const float*)d_in[2];
    const float* Wv = (const float*)d_in[3];
    float* out = (float*)d_out;

    uint16_t* ws = (uint16_t*)d_ws;
    uint16_t* qb = ws;                                   // 16384*128 bf16
    uint16_t* kb = qb + (size_t)16384 * 128;             // 16384*128
    uint16_t* vT = kb + (size_t)16384 * 128;             // 4*128*4096
    uint16_t* WT = vT + (size_t)16384 * 128;             // 3*128*1024

    prep_w<<<dim3((3 * D_ * C_ + 255) / 256), dim3(256), 0, stream>>>(Wq, Wk, Wv, WT);
    qkv_gemm<<<dim3(16384 / 64), dim3(256), 0, stream>>>(x, WT, qb, kb, vT);
    attn<<<dim3(B_ * (T_ / 64)), dim3(256), 0, stream>>>(qb, kb, vT, out);
}